// Round 4
// baseline (561.340 us; speedup 1.0000x reference)
//
#include <hip/hip_runtime.h>
#include <cstdint>

// Problem constants (B,C,D,H,W) = (4,1,192,192,192)
#define NB    4
#define DD    192
#define HH    192
#define WW    192
#define WPR   6                         // 32-bit words per W-row (192/32)
#define NPB   (DD*HH*WW)                // 7,077,888 voxels per batch
#define NWORDS (NB*DD*HH*WPR)           // 884,736 packed words total
#define NELEM (NB*NPB)                  // 28,311,552 voxels total
#define W_CONN 1e-4f

// Spread 8 bits (b7..b0) to bit positions 28,24,...,4,0.
__device__ __forceinline__ uint32_t spread4(uint32_t x) {
    x = (x | (x << 12)) & 0x000F000Fu;
    x = (x | (x << 6))  & 0x03030303u;
    x = (x | (x << 3))  & 0x11111111u;
    return x;
}

// log(1 + exp(-|a|)) using hardware v_exp_f32 / v_log_f32 (base-2).
__device__ __forceinline__ float softplus_neg_abs(float a) {
    const float LOG2E = 1.44269504088896340736f;
    const float LN2   = 0.69314718055994530942f;
    float t = __builtin_amdgcn_exp2f(-fabsf(a) * LOG2E);
    return __builtin_amdgcn_logf(1.0f + t) * LN2;
}

// ---------------- Kernel 1: BCE partial sums + pred bit-pack ----------------
// One thread per float4 (4 consecutive voxels), unit lane stride: each load
// instruction covers 1 KiB contiguous -> full line consumption, no open
// windows, no HBM over-fetch. Bit-pack via wave ballots.
// Block = 256 threads = 1024 voxels; 1024 divides NPB -> block batch-uniform.
__global__ __launch_bounds__(256) void k_bce_pack(
    const float4* __restrict__ x4, const float4* __restrict__ y4,
    uint32_t* __restrict__ bits, float* __restrict__ bce_sum)
{
    const int tid = blockIdx.x * 256 + threadIdx.x;    // float4 id < NELEM/4
    const float4 xv = x4[tid];
    const float4 yv = y4[tid];

    float s = 0.0f;
    uint32_t nib = 0;
    {   float xi = xv.x, yi = yv.x;
        s += fmaxf(xi, 0.0f) - xi * yi + softplus_neg_abs(xi);
        nib |= (xi > 0.0f) ? 1u : 0u; }
    {   float xi = xv.y, yi = yv.y;
        s += fmaxf(xi, 0.0f) - xi * yi + softplus_neg_abs(xi);
        nib |= (xi > 0.0f) ? 2u : 0u; }
    {   float xi = xv.z, yi = yv.z;
        s += fmaxf(xi, 0.0f) - xi * yi + softplus_neg_abs(xi);
        nib |= (xi > 0.0f) ? 4u : 0u; }
    {   float xi = xv.w, yi = yv.w;
        s += fmaxf(xi, 0.0f) - xi * yi + softplus_neg_abs(xi);
        nib |= (xi > 0.0f) ? 8u : 0u; }

    // wave covers 256 consecutive voxels = 8 packed words.
    // element (4*lane + c) -> word (lane>>3), bit (4*(lane&7) + c)
    const uint64_t b0 = __ballot(nib & 1u);
    const uint64_t b1 = __ballot(nib & 2u);
    const uint64_t b2 = __ballot(nib & 4u);
    const uint64_t b3 = __ballot(nib & 8u);

    const int lane = threadIdx.x & 63;
    const int k = lane & 7;                            // which word to assemble
    uint32_t wrd = spread4((uint32_t)(b0 >> (8 * k)) & 0xFFu)
                 | (spread4((uint32_t)(b1 >> (8 * k)) & 0xFFu) << 1)
                 | (spread4((uint32_t)(b2 >> (8 * k)) & 0xFFu) << 2)
                 | (spread4((uint32_t)(b3 >> (8 * k)) & 0xFFu) << 3);
    if (lane < 8) {
        bits[(tid >> 6) * 8 + k] = wrd;
    }

    // block reduction (float)
    __shared__ float red[256];
    red[threadIdx.x] = s;
    __syncthreads();
#pragma unroll
    for (int off = 128; off > 0; off >>= 1) {
        if (threadIdx.x < off) red[threadIdx.x] += red[threadIdx.x + off];
        __syncthreads();
    }
    if (threadIdx.x == 0) {
        const int b = (int)(((long)tid * 4) / (long)NPB); // uniform per block
        atomicAdd(&bce_sum[b], red[0]);
    }
}

// ---------------- Kernel 2: connectivity via bitwise 26-neighbor OR ---------
// Voxel passes iff all 26 periodic neighbors have pred==0
// (acc==pred  <=>  sum of the 26 non-center box entries == 0).
__global__ __launch_bounds__(256) void k_conn(
    const uint32_t* __restrict__ bits, unsigned int* __restrict__ conn_cnt)
{
    const int w = blockIdx.x * 256 + threadIdx.x;      // word id < NWORDS
    const int wi  = w % WPR;
    const int t1  = w / WPR;
    const int yy  = t1 % HH;
    const int t2  = t1 / HH;
    const int zz  = t2 % DD;
    const int b   = t2 / DD;

    const int wiL = (wi == 0)       ? (WPR - 1) : (wi - 1);
    const int wiR = (wi == WPR - 1) ? 0         : (wi + 1);

    const uint32_t* __restrict__ bb = bits + (long)b * (DD * HH * WPR);

    uint32_t n26 = 0;
#pragma unroll
    for (int dz = -1; dz <= 1; ++dz) {
#pragma unroll
        for (int dy = -1; dy <= 1; ++dy) {
            int z2 = zz + dz; if (z2 < 0) z2 += DD; if (z2 >= DD) z2 -= DD;
            int y2 = yy + dy; if (y2 < 0) y2 += HH; if (y2 >= HH) y2 -= HH;
            const uint32_t* row = bb + ((long)z2 * HH + y2) * WPR;
            const uint32_t c = row[wi];
            const uint32_t l = row[wiL];
            const uint32_t r = row[wiR];
            // bit i gets row[i-1] and row[i+1] (periodic across word bounds)
            uint32_t o = ((c << 1) | (l >> 31)) | ((c >> 1) | (r << 31));
            if (!(dz == 0 && dy == 0)) o |= c;         // center row excludes self
            n26 |= o;
        }
    }
    int cnt = 32 - __popc(n26);                        // voxels passing in word

    __shared__ int red[256];
    red[threadIdx.x] = cnt;
    __syncthreads();
#pragma unroll
    for (int off = 128; off > 0; off >>= 1) {
        if (threadIdx.x < off) red[threadIdx.x] += red[threadIdx.x + off];
        __syncthreads();
    }
    if (threadIdx.x == 0) {
        atomicAdd(&conn_cnt[b], (unsigned int)red[0]);
    }
}

// ---------------- Kernel 3: final combine -----------------------------------
__global__ void k_final(const float* __restrict__ is_gt,
                        const float* __restrict__ bce_sum,
                        const unsigned int* __restrict__ conn_cnt,
                        float* __restrict__ out)
{
    if (threadIdx.x == 0 && blockIdx.x == 0) {
        const float inv = 1.0f / (float)NPB;
        float loss = 0.0f;
#pragma unroll
        for (int b = 0; b < NB; ++b) {
            loss += is_gt[b] * (bce_sum[b] * inv)
                  + W_CONN  * ((float)conn_cnt[b] * inv);
        }
        out[0] = loss;
    }
}

extern "C" void kernel_launch(void* const* d_in, const int* in_sizes, int n_in,
                              void* d_out, int out_size, void* d_ws, size_t ws_size,
                              hipStream_t stream) {
    const float* x     = (const float*)d_in[0];
    const float* y     = (const float*)d_in[1];
    const float* is_gt = (const float*)d_in[2];
    float* out = (float*)d_out;

    char* ws = (char*)d_ws;
    float*        bce_sum  = (float*)ws;               // 16 B
    unsigned int* conn_cnt = (unsigned int*)(ws + 64); // 16 B
    uint32_t*     bits     = (uint32_t*)(ws + 256);    // 3.54 MB

    // zero the accumulators (capture-legal)
    hipMemsetAsync(ws, 0, 256, stream);

    const int blocks1 = (NELEM / 4) / 256;             // 27648
    k_bce_pack<<<blocks1, 256, 0, stream>>>(
        (const float4*)x, (const float4*)y, bits, bce_sum);
    const int blocks2 = NWORDS / 256;                  // 3456
    k_conn  <<<blocks2, 256, 0, stream>>>(bits, conn_cnt);
    k_final <<<1, 64, 0, stream>>>(is_gt, bce_sum, conn_cnt, out);
}

// Round 8
// 289.665 us; speedup vs baseline: 1.9379x; 1.9379x over previous
//
#include <hip/hip_runtime.h>
#include <cstdint>

// Problem constants (B,C,D,H,W) = (4,1,192,192,192)
#define NB    4
#define DD    192
#define HH    192
#define WW    192
#define WPR   6                         // 32-bit words per W-row (192/32)
#define NPB   (DD*HH*WW)                // 7,077,888 voxels per batch
#define NWORDS (NB*DD*HH*WPR)           // 884,736 packed words total
#define NELEM (NB*NPB)                  // 28,311,552 voxels total
#define W_CONN 1e-4f

#define ITERS  16                       // float4s per thread in k_bce_pack
#define UNROLL 4                        // independent loads in flight

// Spread 8 bits (b7..b0) to bit positions 28,24,...,4,0.
__device__ __forceinline__ uint32_t spread4(uint32_t x) {
    x = (x | (x << 12)) & 0x000F000Fu;
    x = (x | (x << 6))  & 0x03030303u;
    x = (x | (x << 3))  & 0x11111111u;
    return x;
}

// log(1 + exp(-|a|)) using hardware v_exp_f32 / v_log_f32 (base-2).
__device__ __forceinline__ float softplus_neg_abs(float a) {
    const float LOG2E = 1.44269504088896340736f;
    const float LN2   = 0.69314718055994530942f;
    float t = __builtin_amdgcn_exp2f(-fabsf(a) * LOG2E);
    return __builtin_amdgcn_logf(1.0f + t) * LN2;
}

// ---------------- Kernel 1: BCE partial sums + pred bit-pack ----------------
// Block = 256 threads, processes a CONTIGUOUS chunk of ITERS*1024 = 16384
// voxels (divides NPB -> batch-uniform). Lane stride is unit within each load
// instruction (1 KiB/wave, full line consumption); UNROLL independent
// x4/y4 load pairs in flight per thread restore memory-level parallelism
// (round-4 failure mode: VGPR=12, one 16B load in flight, latency-bound).
__global__ __launch_bounds__(256) void k_bce_pack(
    const float4* __restrict__ x4, const float4* __restrict__ y4,
    uint32_t* __restrict__ bits, float* __restrict__ bce_sum)
{
    const int  t    = threadIdx.x;
    const int  lane = t & 63;
    const int  wid  = t >> 6;
    const long blockBase = (long)blockIdx.x * (ITERS * 256);   // float4 units

    float s = 0.0f;

    for (int it0 = 0; it0 < ITERS; it0 += UNROLL) {
        float4 xa[UNROLL], ya[UNROLL];
#pragma unroll
        for (int u = 0; u < UNROLL; ++u) {
            const long g = blockBase + (long)(it0 + u) * 256 + t;
            xa[u] = x4[g];
            ya[u] = y4[g];
        }
#pragma unroll
        for (int u = 0; u < UNROLL; ++u) {
            const float4 xv = xa[u];
            const float4 yv = ya[u];
            uint32_t nib = 0;
            {   float xi = xv.x, yi = yv.x;
                s += fmaxf(xi, 0.0f) - xi * yi + softplus_neg_abs(xi);
                nib |= (xi > 0.0f) ? 1u : 0u; }
            {   float xi = xv.y, yi = yv.y;
                s += fmaxf(xi, 0.0f) - xi * yi + softplus_neg_abs(xi);
                nib |= (xi > 0.0f) ? 2u : 0u; }
            {   float xi = xv.z, yi = yv.z;
                s += fmaxf(xi, 0.0f) - xi * yi + softplus_neg_abs(xi);
                nib |= (xi > 0.0f) ? 4u : 0u; }
            {   float xi = xv.w, yi = yv.w;
                s += fmaxf(xi, 0.0f) - xi * yi + softplus_neg_abs(xi);
                nib |= (xi > 0.0f) ? 8u : 0u; }

            // wave covers 256 consecutive voxels = 8 packed words.
            // element (4*lane + c) -> word (lane>>3), bit (4*(lane&7) + c)
            const uint64_t b0 = __ballot(nib & 1u);
            const uint64_t b1 = __ballot(nib & 2u);
            const uint64_t b2 = __ballot(nib & 4u);
            const uint64_t b3 = __ballot(nib & 8u);

            const int k = lane & 7;                    // which word to build
            uint32_t wrd = spread4((uint32_t)(b0 >> (8 * k)) & 0xFFu)
                         | (spread4((uint32_t)(b1 >> (8 * k)) & 0xFFu) << 1)
                         | (spread4((uint32_t)(b2 >> (8 * k)) & 0xFFu) << 2)
                         | (spread4((uint32_t)(b3 >> (8 * k)) & 0xFFu) << 3);
            if (lane < 8) {
                const long wordBase =
                    (blockBase + (long)(it0 + u) * 256 + ((long)wid << 6)) >> 3;
                bits[wordBase + k] = wrd;
            }
        }
    }

    // wave-level shuffle reduce (no barriers), then 4 -> 1 via LDS
    for (int off = 32; off > 0; off >>= 1) s += __shfl_down(s, off);
    __shared__ float red[4];
    if (lane == 0) red[wid] = s;
    __syncthreads();
    if (t == 0) {
        const float tot = red[0] + red[1] + red[2] + red[3];
        const int b = (int)((blockBase * 4) / (long)NPB);  // uniform per block
        atomicAdd(&bce_sum[b], tot);
    }
}

// ---------------- Kernel 2: connectivity via bitwise 26-neighbor OR ---------
// Voxel passes iff all 26 periodic neighbors have pred==0
// (acc==pred  <=>  sum of the 26 non-center box entries == 0).
__global__ __launch_bounds__(256) void k_conn(
    const uint32_t* __restrict__ bits, unsigned int* __restrict__ conn_cnt)
{
    const int w = blockIdx.x * 256 + threadIdx.x;      // word id < NWORDS
    const int wi  = w % WPR;
    const int t1  = w / WPR;
    const int yy  = t1 % HH;
    const int t2  = t1 / HH;
    const int zz  = t2 % DD;
    const int b   = t2 / DD;

    const int wiL = (wi == 0)       ? (WPR - 1) : (wi - 1);
    const int wiR = (wi == WPR - 1) ? 0         : (wi + 1);

    const uint32_t* __restrict__ bb = bits + (long)b * (DD * HH * WPR);

    uint32_t n26 = 0;
#pragma unroll
    for (int dz = -1; dz <= 1; ++dz) {
#pragma unroll
        for (int dy = -1; dy <= 1; ++dy) {
            int z2 = zz + dz; if (z2 < 0) z2 += DD; if (z2 >= DD) z2 -= DD;
            int y2 = yy + dy; if (y2 < 0) y2 += HH; if (y2 >= HH) y2 -= HH;
            const uint32_t* row = bb + ((long)z2 * HH + y2) * WPR;
            const uint32_t c = row[wi];
            const uint32_t l = row[wiL];
            const uint32_t r = row[wiR];
            // bit i gets row[i-1] and row[i+1] (periodic across word bounds)
            uint32_t o = ((c << 1) | (l >> 31)) | ((c >> 1) | (r << 31));
            if (!(dz == 0 && dy == 0)) o |= c;         // center row excludes self
            n26 |= o;
        }
    }
    int cnt = 32 - __popc(n26);                        // voxels passing in word

    // wave reduce + LDS combine
    for (int off = 32; off > 0; off >>= 1) cnt += __shfl_down(cnt, off);
    __shared__ int red[4];
    const int lane = threadIdx.x & 63;
    const int wid  = threadIdx.x >> 6;
    if (lane == 0) red[wid] = cnt;
    __syncthreads();
    if (threadIdx.x == 0) {
        atomicAdd(&conn_cnt[b], (unsigned int)(red[0] + red[1] + red[2] + red[3]));
    }
}

// ---------------- Kernel 3: final combine -----------------------------------
__global__ void k_final(const float* __restrict__ is_gt,
                        const float* __restrict__ bce_sum,
                        const unsigned int* __restrict__ conn_cnt,
                        float* __restrict__ out)
{
    if (threadIdx.x == 0 && blockIdx.x == 0) {
        const float inv = 1.0f / (float)NPB;
        float loss = 0.0f;
#pragma unroll
        for (int b = 0; b < NB; ++b) {
            loss += is_gt[b] * (bce_sum[b] * inv)
                  + W_CONN  * ((float)conn_cnt[b] * inv);
        }
        out[0] = loss;
    }
}

extern "C" void kernel_launch(void* const* d_in, const int* in_sizes, int n_in,
                              void* d_out, int out_size, void* d_ws, size_t ws_size,
                              hipStream_t stream) {
    const float* x     = (const float*)d_in[0];
    const float* y     = (const float*)d_in[1];
    const float* is_gt = (const float*)d_in[2];
    float* out = (float*)d_out;

    char* ws = (char*)d_ws;
    float*        bce_sum  = (float*)ws;               // 16 B
    unsigned int* conn_cnt = (unsigned int*)(ws + 64); // 16 B
    uint32_t*     bits     = (uint32_t*)(ws + 256);    // 3.54 MB

    // zero the accumulators (capture-legal)
    hipMemsetAsync(ws, 0, 256, stream);

    const int blocks1 = (NELEM / 4) / (ITERS * 256);   // 1728
    k_bce_pack<<<blocks1, 256, 0, stream>>>(
        (const float4*)x, (const float4*)y, bits, bce_sum);
    const int blocks2 = NWORDS / 256;                  // 3456
    k_conn  <<<blocks2, 256, 0, stream>>>(bits, conn_cnt);
    k_final <<<1, 64, 0, stream>>>(is_gt, bce_sum, conn_cnt, out);
}